// Round 5
// baseline (971.427 us; speedup 1.0000x reference)
//
#include <hip/hip_runtime.h>

#define IN_FT   4096
#define OUT_FT  4096
#define B_SZ    256
#define NNZ_T   500000
#define NNZ_N   100000
#define NNZ_TOT 600000
#define QTR_N   150000              // entries per quarter
#define QTR4    (QTR_N / 2)         // 75000 uint4 (2 entries each)
#define ROWS_PB 64                  // output rows per block slice
#define QCAP    4096                // LDS queue capacity (mean fill 2344, 36 sigma)
#define ACC_LD  257                 // padded leading dim: bank = (rr+b)&31

// ---- workspace layout (bytes) ----
#define OFF_ENT  0u                 // 600000 * 8B packed (rc, val) = 4,800,000
#define OFF_XT   4800000u           // 4096*256 f32 = 4,194,304
#define OFF_FLAG 8994304u           // 2 i32: idx buffers are int64?

// ---------------------------------------------------------------------------
// out[b][r] = bias[r]; detect int64 vs int32 index buffers.   [validated R1/R2]
__global__ __launch_bounds__(256) void k_init(const float* __restrict__ bias,
                                              float* __restrict__ out,
                                              const int* __restrict__ st_idx,
                                              const int* __restrict__ sn_idx,
                                              int* __restrict__ flag) {
    int i = blockIdx.x * 256 + threadIdx.x;            // grid = 1024 blocks
    float4* out4 = (float4*)out;
    const float4* bias4 = (const float4*)bias;
    out4[i] = bias4[i & 1023];
    if (blockIdx.x == 0) {
        __shared__ int nz_t, nz_n;
        if (threadIdx.x == 0) { nz_t = 0; nz_n = 0; }
        __syncthreads();
        // if idx is int64, every odd 32-bit word is 0 (all values < 4096)
        if (st_idx[2 * threadIdx.x + 1] != 0) atomicAdd(&nz_t, 1);
        if (sn_idx[2 * threadIdx.x + 1] != 0) atomicAdd(&nz_n, 1);
        __syncthreads();
        if (threadIdx.x == 0) { flag[0] = (nz_t == 0); flag[1] = (nz_n == 0); }
    }
}

// ---------------------------------------------------------------------------
// tiled transpose: x (256 x 4096) -> xT (4096 x 256), f32    [validated R1]
__global__ __launch_bounds__(256) void k_transpose(const float* __restrict__ in,
                                                   float* __restrict__ out,
                                                   int rows, int cols) {
    __shared__ float tile[32][33];
    int x0 = blockIdx.x * 32;   // col block in 'in'
    int y0 = blockIdx.y * 32;   // row block in 'in'
    int tx = threadIdx.x, ty = threadIdx.y;   // (32, 8)
    #pragma unroll
    for (int j = 0; j < 32; j += 8)
        tile[ty + j][tx] = in[(size_t)(y0 + ty + j) * cols + (x0 + tx)];
    __syncthreads();
    #pragma unroll
    for (int j = 0; j < 32; j += 8)
        out[(size_t)(x0 + ty + j) * rows + (y0 + tx)] = tile[tx][ty + j];
}

// ---------------------------------------------------------------------------
__device__ __forceinline__ void get_entry(int i,
                                          const int* __restrict__ st_idx,
                                          const float* __restrict__ st_vals,
                                          const int* __restrict__ sn_idx,
                                          const float* __restrict__ sn_vals,
                                          int stride_t, int stride_n,
                                          int& row, int& col, float& val) {
    if (i < NNZ_T) {
        row = st_idx[(size_t)i * stride_t];
        col = st_idx[(size_t)(NNZ_T + i) * stride_t];
        val = st_vals[i];
    } else {
        int j = i - NNZ_T;
        row = sn_idx[(size_t)j * stride_n];
        col = sn_idx[(size_t)(NNZ_N + j) * stride_n];
        val = sn_vals[j];
    }
}

// pack all nnz into 8B records: (row<<12 | col, val_bits)     [validated R2]
__global__ __launch_bounds__(256) void k_pack(const int* __restrict__ st_idx,
                                              const float* __restrict__ st_vals,
                                              const int* __restrict__ sn_idx,
                                              const float* __restrict__ sn_vals,
                                              const int* __restrict__ flag,
                                              uint2* __restrict__ ent) {
    int i = blockIdx.x * 256 + threadIdx.x;
    if (i >= NNZ_TOT) return;
    int s_t = flag[0] ? 2 : 1, s_n = flag[1] ? 2 : 1;
    int row, col; float val;
    get_entry(i, st_idx, st_vals, sn_idx, sn_vals, s_t, s_n, row, col, val);
    ent[i] = make_uint2(((unsigned)row << 12) | (unsigned)col, __float_as_uint(val));
}

// ---------------------------------------------------------------------------
// 256 blocks x 1024 threads. Block = (row slice [R0,R0+64), entry quarter qi).
// Phase 1: stream quarter, push matching entries into LDS queue (no shfl).
// Phase 2: one queue entry per wave; 64 lanes x 4 MAC into padded LDS acc.
// qi = blockIdx&3 so each XCD (%8 round-robin) streams ONE 1.2MB quarter.
__global__ __launch_bounds__(1024) void k_gq(const float* __restrict__ xT,
                                             const uint2* __restrict__ ent,
                                             float* __restrict__ out) {
    extern __shared__ char smem[];
    float* acc   = (float*)smem;                        // 64*257 f32 = 65792B
    uint2* queue = (uint2*)(smem + 65792);              // 4096*8   = 32768B
    __shared__ int qcount;
    const int t = threadIdx.x;
    const int lane = t & 63;
    const int wave = t >> 6;
    const int qi = blockIdx.x & 3;
    const unsigned R0 = (unsigned)(blockIdx.x >> 2) * ROWS_PB;

    #pragma unroll
    for (int k = 0; k < (ROWS_PB * ACC_LD + 1023) / 1024; ++k) {
        int c = t + k * 1024;
        if (c < ROWS_PB * ACC_LD) acc[c] = 0.f;
    }
    if (t == 0) qcount = 0;
    __syncthreads();

    // ---- phase 1: filter ----
    const uint4* ep = (const uint4*)(ent + (size_t)qi * QTR_N);
    for (int i = t; i < QTR4; i += 1024) {
        uint4 e = ep[i];
        if (((e.x >> 12) - R0) < ROWS_PB) {
            int p = atomicAdd(&qcount, 1);
            if (p < QCAP) queue[p] = make_uint2(e.x, e.y);
        }
        if (((e.z >> 12) - R0) < ROWS_PB) {
            int p = atomicAdd(&qcount, 1);
            if (p < QCAP) queue[p] = make_uint2(e.z, e.w);
        }
    }
    __syncthreads();
    const int qn = min(qcount, QCAP);

    // ---- phase 2: one entry per wave, rank-1 update ----
    for (int j = wave; j < qn; j += 16) {
        uint2 e = queue[j];                              // LDS broadcast
        float v = __uint_as_float(e.y);
        unsigned rr = (e.x >> 12) - R0;
        const float* xc = xT + (size_t)(e.x & 4095u) * B_SZ;
        float* arow = acc + rr * ACC_LD;
        #pragma unroll
        for (int k2 = 0; k2 < 4; ++k2) {
            int b = lane + 64 * k2;
            atomicAdd(&arow[b], v * xc[b]);   // ds_add_f32, bank=(rr+lane)&31: 2-way
        }
    }
    __syncthreads();

    // ---- flush: out[b][R0+rr] += acc[rr][b] (out pre-filled with bias) ----
    #pragma unroll
    for (int k = 0; k < 16; ++k) {
        int cell = t + k * 1024;             // 16384 = 64 rows x 256 batch
        int rr = cell & 63, b = cell >> 6;   // lanes: consecutive rr -> coalesced out
        unsafeAtomicAdd(&out[(size_t)b * OUT_FT + R0 + rr], acc[rr * ACC_LD + b]);
    }
}

// ---------------------------------------------------------------------------
extern "C" void kernel_launch(void* const* d_in, const int* in_sizes, int n_in,
                              void* d_out, int out_size, void* d_ws, size_t ws_size,
                              hipStream_t stream) {
    const float* x       = (const float*)d_in[0];
    const int*   st_idx  = (const int*)d_in[1];
    const float* st_vals = (const float*)d_in[2];
    const int*   sn_idx  = (const int*)d_in[3];
    const float* sn_vals = (const float*)d_in[4];
    const float* bias    = (const float*)d_in[5];
    float* out = (float*)d_out;

    char* ws = (char*)d_ws;
    uint2* ent  = (uint2*)(ws + OFF_ENT);
    float* xT   = (float*)(ws + OFF_XT);
    int*   flag = (int*)  (ws + OFF_FLAG);

    (void)hipFuncSetAttribute((const void*)k_gq,
                              hipFuncAttributeMaxDynamicSharedMemorySize,
                              65792 + 32768);

    k_init<<<(B_SZ * OUT_FT / 4) / 256, 256, 0, stream>>>(bias, out, st_idx, sn_idx, flag);
    k_transpose<<<dim3(IN_FT / 32, B_SZ / 32), dim3(32, 8), 0, stream>>>(x, xT, B_SZ, IN_FT);
    k_pack<<<(NNZ_TOT + 255) / 256, 256, 0, stream>>>(st_idx, st_vals, sn_idx, sn_vals,
                                                      flag, ent);
    k_gq<<<256, 1024, 65792 + 32768, stream>>>(xT, ent, out);
}

// Round 6
// 151.300 us; speedup vs baseline: 6.4205x; 6.4205x over previous
//
#include <hip/hip_runtime.h>

#define IN_FT   4096
#define OUT_FT  4096
#define B_SZ    256
#define NNZ_T   500000
#define NNZ_N   100000
#define NNZ_TOT 600000
#define QTR_N   150000              // entries per quarter
#define QTR4    (QTR_N / 2)         // 75000 uint4 (2 entries each)
#define ROWS_PB 64                  // output rows per block slice
#define QROW_CAP 256                // per-row queue capacity (mean 37, 36 sigma)
#define ACC_LD  257                 // padded acc leading dim: bank = (rr+b)&31

// ---- workspace layout (bytes) ----
#define OFF_ENT  0u                 // 600000 * 8B packed (rc, val) = 4,800,000
#define OFF_XT   4800000u           // 4096*256 f32 = 4,194,304
#define OFF_FLAG 8994304u           // 2 i32: idx buffers are int64?

// ---------------------------------------------------------------------------
// out[b][r] = bias[r]; detect int64 vs int32 index buffers.   [validated R1/R2/R5]
__global__ __launch_bounds__(256) void k_init(const float* __restrict__ bias,
                                              float* __restrict__ out,
                                              const int* __restrict__ st_idx,
                                              const int* __restrict__ sn_idx,
                                              int* __restrict__ flag) {
    int i = blockIdx.x * 256 + threadIdx.x;            // grid = 1024 blocks
    float4* out4 = (float4*)out;
    const float4* bias4 = (const float4*)bias;
    out4[i] = bias4[i & 1023];
    if (blockIdx.x == 0) {
        __shared__ int nz_t, nz_n;
        if (threadIdx.x == 0) { nz_t = 0; nz_n = 0; }
        __syncthreads();
        // if idx is int64, every odd 32-bit word is 0 (all values < 4096)
        if (st_idx[2 * threadIdx.x + 1] != 0) atomicAdd(&nz_t, 1);
        if (sn_idx[2 * threadIdx.x + 1] != 0) atomicAdd(&nz_n, 1);
        __syncthreads();
        if (threadIdx.x == 0) { flag[0] = (nz_t == 0); flag[1] = (nz_n == 0); }
    }
}

// ---------------------------------------------------------------------------
// tiled transpose: x (256 x 4096) -> xT (4096 x 256), f32    [validated R1/R5]
__global__ __launch_bounds__(256) void k_transpose(const float* __restrict__ in,
                                                   float* __restrict__ out,
                                                   int rows, int cols) {
    __shared__ float tile[32][33];
    int x0 = blockIdx.x * 32;   // col block in 'in'
    int y0 = blockIdx.y * 32;   // row block in 'in'
    int tx = threadIdx.x, ty = threadIdx.y;   // (32, 8)
    #pragma unroll
    for (int j = 0; j < 32; j += 8)
        tile[ty + j][tx] = in[(size_t)(y0 + ty + j) * cols + (x0 + tx)];
    __syncthreads();
    #pragma unroll
    for (int j = 0; j < 32; j += 8)
        out[(size_t)(x0 + ty + j) * rows + (y0 + tx)] = tile[tx][ty + j];
}

// ---------------------------------------------------------------------------
__device__ __forceinline__ void get_entry(int i,
                                          const int* __restrict__ st_idx,
                                          const float* __restrict__ st_vals,
                                          const int* __restrict__ sn_idx,
                                          const float* __restrict__ sn_vals,
                                          int stride_t, int stride_n,
                                          int& row, int& col, float& val) {
    if (i < NNZ_T) {
        row = st_idx[(size_t)i * stride_t];
        col = st_idx[(size_t)(NNZ_T + i) * stride_t];
        val = st_vals[i];
    } else {
        int j = i - NNZ_T;
        row = sn_idx[(size_t)j * stride_n];
        col = sn_idx[(size_t)(NNZ_N + j) * stride_n];
        val = sn_vals[j];
    }
}

// pack all nnz into 8B records: (row<<12 | col, val_bits)     [validated R2/R5]
__global__ __launch_bounds__(256) void k_pack(const int* __restrict__ st_idx,
                                              const float* __restrict__ st_vals,
                                              const int* __restrict__ sn_idx,
                                              const float* __restrict__ sn_vals,
                                              const int* __restrict__ flag,
                                              uint2* __restrict__ ent) {
    int i = blockIdx.x * 256 + threadIdx.x;
    if (i >= NNZ_TOT) return;
    int s_t = flag[0] ? 2 : 1, s_n = flag[1] ? 2 : 1;
    int row, col; float val;
    get_entry(i, st_idx, st_vals, sn_idx, sn_vals, s_t, s_n, row, col, val);
    ent[i] = make_uint2(((unsigned)row << 12) | (unsigned)col, __float_as_uint(val));
}

// ---------------------------------------------------------------------------
// 256 blocks x 1024 threads. Block = (row slice [R0,R0+64), entry quarter qi).
// Phase 1: filter quarter into 64 per-row LDS queues (int cursor atomics only).
// Phase 2: wave w owns rows 4w..4w+3 -> pure-register FMA accumulation, NO
//          LDS atomics (R2/R5 showed ds_add_f32 costs ~200cy/wave-instr).
// Phase 3: regs -> LDS (queue space reused), coalesced atomic flush to out.
__global__ __launch_bounds__(1024) void k_gf(const float* __restrict__ xT,
                                             const uint2* __restrict__ ent,
                                             float* __restrict__ out) {
    extern __shared__ char smem[];
    uint2* queues = (uint2*)smem;          // 64 * 256 * 8B = 131072
    float* acc    = (float*)smem;          // reused after phase 2: 64*257*4 = 65792
    __shared__ int cnt_s[ROWS_PB];
    const int t = threadIdx.x;
    const int lane = t & 63;
    const int wave = t >> 6;               // 16 waves
    const int qi = blockIdx.x & 3;
    const unsigned R0 = (unsigned)(blockIdx.x >> 2) * ROWS_PB;

    if (t < ROWS_PB) cnt_s[t] = 0;
    __syncthreads();

    // ---- phase 1: filter into per-row queues ----
    const uint4* ep = (const uint4*)(ent + (size_t)qi * QTR_N);
    for (int i = t; i < QTR4; i += 1024) {
        uint4 e = ep[i];
        unsigned r0 = (e.x >> 12) - R0;
        if (r0 < (unsigned)ROWS_PB) {
            int p = atomicAdd(&cnt_s[r0], 1);
            if (p < QROW_CAP) queues[r0 * QROW_CAP + p] = make_uint2(e.x, e.y);
        }
        unsigned r1 = (e.z >> 12) - R0;
        if (r1 < (unsigned)ROWS_PB) {
            int p = atomicAdd(&cnt_s[r1], 1);
            if (p < QROW_CAP) queues[r1 * QROW_CAP + p] = make_uint2(e.z, e.w);
        }
    }
    __syncthreads();

    // ---- phase 2: register accumulation, wave-owned rows ----
    float4 av[4] = {{0.f,0.f,0.f,0.f},{0.f,0.f,0.f,0.f},
                    {0.f,0.f,0.f,0.f},{0.f,0.f,0.f,0.f}};
    #pragma unroll
    for (int r = 0; r < 4; ++r) {
        const int q = wave * 4 + r;
        const int n = min(cnt_s[q], QROW_CAP);
        const uint2* qr = queues + q * QROW_CAP;
        uint2 e0 = make_uint2(0u, 0u);
        if (n > 0) e0 = qr[0];
        for (int j = 0; j < n; ++j) {
            uint2 e1 = make_uint2(0u, 0u);
            if (j + 1 < n) e1 = qr[j + 1];                 // depth-1 prefetch
            unsigned rc = __builtin_amdgcn_readfirstlane(e0.x);
            float v = __uint_as_float(__builtin_amdgcn_readfirstlane(e0.y));
            const float4* xc = (const float4*)(xT + (size_t)(rc & 4095u) * B_SZ);
            float4 xv = xc[lane];                          // coalesced 1KB/wave
            av[r].x = fmaf(v, xv.x, av[r].x);
            av[r].y = fmaf(v, xv.y, av[r].y);
            av[r].z = fmaf(v, xv.z, av[r].z);
            av[r].w = fmaf(v, xv.w, av[r].w);
            e0 = e1;
        }
    }
    __syncthreads();   // all queue reads done before LDS reuse

    // ---- phase 3a: regs -> LDS acc[rr][b], b = 4*lane..4*lane+3 ----
    #pragma unroll
    for (int r = 0; r < 4; ++r) {
        int rr = wave * 4 + r;
        float* arow = acc + rr * ACC_LD + 4 * lane;
        arow[0] = av[r].x; arow[1] = av[r].y; arow[2] = av[r].z; arow[3] = av[r].w;
    }
    __syncthreads();

    // ---- phase 3b: coalesced flush (out pre-filled with bias) [validated R5] ----
    #pragma unroll
    for (int k = 0; k < 16; ++k) {
        int cell = t + k * 1024;             // 16384 = 64 rows x 256 batch
        int rr = cell & 63, b = cell >> 6;   // consecutive rr per lane -> coalesced
        unsafeAtomicAdd(&out[(size_t)b * OUT_FT + R0 + rr], acc[rr * ACC_LD + b]);
    }
}

// ---------------------------------------------------------------------------
extern "C" void kernel_launch(void* const* d_in, const int* in_sizes, int n_in,
                              void* d_out, int out_size, void* d_ws, size_t ws_size,
                              hipStream_t stream) {
    const float* x       = (const float*)d_in[0];
    const int*   st_idx  = (const int*)d_in[1];
    const float* st_vals = (const float*)d_in[2];
    const int*   sn_idx  = (const int*)d_in[3];
    const float* sn_vals = (const float*)d_in[4];
    const float* bias    = (const float*)d_in[5];
    float* out = (float*)d_out;

    char* ws = (char*)d_ws;
    uint2* ent  = (uint2*)(ws + OFF_ENT);
    float* xT   = (float*)(ws + OFF_XT);
    int*   flag = (int*)  (ws + OFF_FLAG);

    (void)hipFuncSetAttribute((const void*)k_gf,
                              hipFuncAttributeMaxDynamicSharedMemorySize, 131072);

    k_init<<<(B_SZ * OUT_FT / 4) / 256, 256, 0, stream>>>(bias, out, st_idx, sn_idx, flag);
    k_transpose<<<dim3(IN_FT / 32, B_SZ / 32), dim3(32, 8), 0, stream>>>(x, xT, B_SZ, IN_FT);
    k_pack<<<(NNZ_TOT + 255) / 256, 256, 0, stream>>>(st_idx, st_vals, sn_idx, sn_vals,
                                                      flag, ent);
    k_gf<<<256, 1024, 131072, stream>>>(xT, ent, out);
}

// Round 8
// 141.272 us; speedup vs baseline: 6.8763x; 1.0710x over previous
//
#include <hip/hip_runtime.h>

#define IN_FT   4096
#define OUT_FT  4096
#define B_SZ    256
#define NNZ_T   500000
#define NNZ_N   100000
#define NNZ_TOT 600000
#define QTR_N   150000              // entries per quarter
#define QTR4    (QTR_N / 2)         // 75000 uint4 (2 entries each)
#define ROWS_PB 64                  // output rows per block slice
#define QROW_CAP 256                // per-row queue capacity (mean 37, 36 sigma)
#define ACC_LD  257                 // padded acc leading dim: bank = (rr+b)&31

// ---- workspace layout (bytes) ----
#define OFF_ENT  0u                 // 600000 * 8B packed (rc, val) = 4,800,000
#define OFF_XT   4800000u           // 4096*256 f32 = 4,194,304
#define OFF_FLAG 8994304u           // 2 i32: idx buffers are int64?

// ---------------------------------------------------------------------------
// out[b][r] = bias[r]; detect int64 vs int32 index buffers.   [validated R1/R2/R5/R6]
__global__ __launch_bounds__(256) void k_init(const float* __restrict__ bias,
                                              float* __restrict__ out,
                                              const int* __restrict__ st_idx,
                                              const int* __restrict__ sn_idx,
                                              int* __restrict__ flag) {
    int i = blockIdx.x * 256 + threadIdx.x;            // grid = 1024 blocks
    float4* out4 = (float4*)out;
    const float4* bias4 = (const float4*)bias;
    out4[i] = bias4[i & 1023];
    if (blockIdx.x == 0) {
        __shared__ int nz_t, nz_n;
        if (threadIdx.x == 0) { nz_t = 0; nz_n = 0; }
        __syncthreads();
        // if idx is int64, every odd 32-bit word is 0 (all values < 4096)
        if (st_idx[2 * threadIdx.x + 1] != 0) atomicAdd(&nz_t, 1);
        if (sn_idx[2 * threadIdx.x + 1] != 0) atomicAdd(&nz_n, 1);
        __syncthreads();
        if (threadIdx.x == 0) { flag[0] = (nz_t == 0); flag[1] = (nz_n == 0); }
    }
}

// ---------------------------------------------------------------------------
// tiled transpose: x (256 x 4096) -> xT (4096 x 256), f32    [validated R1/R5/R6]
__global__ __launch_bounds__(256) void k_transpose(const float* __restrict__ in,
                                                   float* __restrict__ out,
                                                   int rows, int cols) {
    __shared__ float tile[32][33];
    int x0 = blockIdx.x * 32;   // col block in 'in'
    int y0 = blockIdx.y * 32;   // row block in 'in'
    int tx = threadIdx.x, ty = threadIdx.y;   // (32, 8)
    #pragma unroll
    for (int j = 0; j < 32; j += 8)
        tile[ty + j][tx] = in[(size_t)(y0 + ty + j) * cols + (x0 + tx)];
    __syncthreads();
    #pragma unroll
    for (int j = 0; j < 32; j += 8)
        out[(size_t)(x0 + ty + j) * rows + (y0 + tx)] = tile[tx][ty + j];
}

// ---------------------------------------------------------------------------
__device__ __forceinline__ void get_entry(int i,
                                          const int* __restrict__ st_idx,
                                          const float* __restrict__ st_vals,
                                          const int* __restrict__ sn_idx,
                                          const float* __restrict__ sn_vals,
                                          int stride_t, int stride_n,
                                          int& row, int& col, float& val) {
    if (i < NNZ_T) {
        row = st_idx[(size_t)i * stride_t];
        col = st_idx[(size_t)(NNZ_T + i) * stride_t];
        val = st_vals[i];
    } else {
        int j = i - NNZ_T;
        row = sn_idx[(size_t)j * stride_n];
        col = sn_idx[(size_t)(NNZ_N + j) * stride_n];
        val = sn_vals[j];
    }
}

// pack all nnz into 8B records: (row<<12 | col, val_bits)     [validated R2/R5/R6]
__global__ __launch_bounds__(256) void k_pack(const int* __restrict__ st_idx,
                                              const float* __restrict__ st_vals,
                                              const int* __restrict__ sn_idx,
                                              const float* __restrict__ sn_vals,
                                              const int* __restrict__ flag,
                                              uint2* __restrict__ ent) {
    int i = blockIdx.x * 256 + threadIdx.x;
    if (i >= NNZ_TOT) return;
    int s_t = flag[0] ? 2 : 1, s_n = flag[1] ? 2 : 1;
    int row, col; float val;
    get_entry(i, st_idx, st_vals, sn_idx, sn_vals, s_t, s_n, row, col, val);
    ent[i] = make_uint2(((unsigned)row << 12) | (unsigned)col, __float_as_uint(val));
}

// ---------------------------------------------------------------------------
// 256 blocks x 1024 threads. Block = (row slice [R0,R0+64), entry quarter qi).
// Phase 1: filter quarter into 64 per-row LDS queues (int cursor atomics only).
// Phase 2: wave w owns rows 4w..4w+3 -> register FMA accumulation with 4-way
//          row interleave (4 independent gathers in flight; R6 showed the
//          serial per-entry chain left VALU at 23% waiting on L2 latency).
// Phase 3: regs -> LDS (queue space reused), coalesced atomic flush to out.
__global__ __launch_bounds__(1024) void k_gf(const float* __restrict__ xT,
                                             const uint2* __restrict__ ent,
                                             float* __restrict__ out) {
    extern __shared__ char smem[];
    uint2* queues = (uint2*)smem;          // 64 * 256 * 8B = 131072
    float* acc    = (float*)smem;          // reused after phase 2: 64*257*4 = 65792
    __shared__ int cnt_s[ROWS_PB];
    const int t = threadIdx.x;
    const int lane = t & 63;
    const int wave = t >> 6;               // 16 waves
    const int qi = blockIdx.x & 3;
    const unsigned R0 = (unsigned)(blockIdx.x >> 2) * ROWS_PB;

    if (t < ROWS_PB) cnt_s[t] = 0;
    __syncthreads();

    // ---- phase 1: filter into per-row queues ----
    const uint4* ep = (const uint4*)(ent + (size_t)qi * QTR_N);
    for (int i = t; i < QTR4; i += 1024) {
        uint4 e = ep[i];
        unsigned r0 = (e.x >> 12) - R0;
        if (r0 < (unsigned)ROWS_PB) {
            int p = atomicAdd(&cnt_s[r0], 1);
            if (p < QROW_CAP) queues[r0 * QROW_CAP + p] = make_uint2(e.x, e.y);
        }
        unsigned r1 = (e.z >> 12) - R0;
        if (r1 < (unsigned)ROWS_PB) {
            int p = atomicAdd(&cnt_s[r1], 1);
            if (p < QROW_CAP) queues[r1 * QROW_CAP + p] = make_uint2(e.z, e.w);
        }
    }
    __syncthreads();

    // ---- phase 2: 4-row-interleaved register accumulation (no LDS atomics) ----
    float4 av0 = {0.f,0.f,0.f,0.f}, av1 = av0, av2 = av0, av3 = av0;
    {
        const int q = wave * 4;
        const int n0 = min(cnt_s[q + 0], QROW_CAP);
        const int n1 = min(cnt_s[q + 1], QROW_CAP);
        const int n2 = min(cnt_s[q + 2], QROW_CAP);
        const int n3 = min(cnt_s[q + 3], QROW_CAP);
        const uint2* q0 = queues + (q + 0) * QROW_CAP;
        const uint2* q1 = queues + (q + 1) * QROW_CAP;
        const uint2* q2 = queues + (q + 2) * QROW_CAP;
        const uint2* q3 = queues + (q + 3) * QROW_CAP;
        const int nmax = max(max(n0, n1), max(n2, n3));
        #pragma unroll 2
        for (int j = 0; j < nmax; ++j) {
            // tail guard via zero-val: load stays unconditional -> stays pipelined
            uint2 e0 = (j < n0) ? q0[j] : make_uint2(0u, 0u);
            uint2 e1 = (j < n1) ? q1[j] : make_uint2(0u, 0u);
            uint2 e2 = (j < n2) ? q2[j] : make_uint2(0u, 0u);
            uint2 e3 = (j < n3) ? q3[j] : make_uint2(0u, 0u);
            const float4* p0 = (const float4*)(xT + (size_t)(e0.x & 4095u) * B_SZ);
            const float4* p1 = (const float4*)(xT + (size_t)(e1.x & 4095u) * B_SZ);
            const float4* p2 = (const float4*)(xT + (size_t)(e2.x & 4095u) * B_SZ);
            const float4* p3 = (const float4*)(xT + (size_t)(e3.x & 4095u) * B_SZ);
            float4 x0 = p0[lane];              // 4 independent coalesced 1KB gathers
            float4 x1 = p1[lane];
            float4 x2 = p2[lane];
            float4 x3 = p3[lane];
            float v0 = __uint_as_float(e0.y);
            float v1 = __uint_as_float(e1.y);
            float v2 = __uint_as_float(e2.y);
            float v3 = __uint_as_float(e3.y);
            av0.x = fmaf(v0, x0.x, av0.x); av0.y = fmaf(v0, x0.y, av0.y);
            av0.z = fmaf(v0, x0.z, av0.z); av0.w = fmaf(v0, x0.w, av0.w);
            av1.x = fmaf(v1, x1.x, av1.x); av1.y = fmaf(v1, x1.y, av1.y);
            av1.z = fmaf(v1, x1.z, av1.z); av1.w = fmaf(v1, x1.w, av1.w);
            av2.x = fmaf(v2, x2.x, av2.x); av2.y = fmaf(v2, x2.y, av2.y);
            av2.z = fmaf(v2, x2.z, av2.z); av2.w = fmaf(v2, x2.w, av2.w);
            av3.x = fmaf(v3, x3.x, av3.x); av3.y = fmaf(v3, x3.y, av3.y);
            av3.z = fmaf(v3, x3.z, av3.z); av3.w = fmaf(v3, x3.w, av3.w);
        }
    }
    __syncthreads();   // all queue reads done before LDS reuse

    // ---- phase 3a: regs -> LDS acc[rr][b], b = 4*lane..4*lane+3 ----
    {
        float* a0 = acc + (wave * 4 + 0) * ACC_LD + 4 * lane;
        float* a1 = acc + (wave * 4 + 1) * ACC_LD + 4 * lane;
        float* a2 = acc + (wave * 4 + 2) * ACC_LD + 4 * lane;
        float* a3 = acc + (wave * 4 + 3) * ACC_LD + 4 * lane;
        a0[0] = av0.x; a0[1] = av0.y; a0[2] = av0.z; a0[3] = av0.w;
        a1[0] = av1.x; a1[1] = av1.y; a1[2] = av1.z; a1[3] = av1.w;
        a2[0] = av2.x; a2[1] = av2.y; a2[2] = av2.z; a2[3] = av2.w;
        a3[0] = av3.x; a3[1] = av3.y; a3[2] = av3.z; a3[3] = av3.w;
    }
    __syncthreads();

    // ---- phase 3b: coalesced flush (out pre-filled with bias) [validated R5/R6] ----
    #pragma unroll
    for (int k = 0; k < 16; ++k) {
        int cell = t + k * 1024;             // 16384 = 64 rows x 256 batch
        int rr = cell & 63, b = cell >> 6;   // consecutive rr per lane -> coalesced
        unsafeAtomicAdd(&out[(size_t)b * OUT_FT + R0 + rr], acc[rr * ACC_LD + b]);
    }
}

// ---------------------------------------------------------------------------
extern "C" void kernel_launch(void* const* d_in, const int* in_sizes, int n_in,
                              void* d_out, int out_size, void* d_ws, size_t ws_size,
                              hipStream_t stream) {
    const float* x       = (const float*)d_in[0];
    const int*   st_idx  = (const int*)d_in[1];
    const float* st_vals = (const float*)d_in[2];
    const int*   sn_idx  = (const int*)d_in[3];
    const float* sn_vals = (const float*)d_in[4];
    const float* bias    = (const float*)d_in[5];
    float* out = (float*)d_out;

    char* ws = (char*)d_ws;
    uint2* ent  = (uint2*)(ws + OFF_ENT);
    float* xT   = (float*)(ws + OFF_XT);
    int*   flag = (int*)  (ws + OFF_FLAG);

    (void)hipFuncSetAttribute((const void*)k_gf,
                              hipFuncAttributeMaxDynamicSharedMemorySize, 131072);

    k_init<<<(B_SZ * OUT_FT / 4) / 256, 256, 0, stream>>>(bias, out, st_idx, sn_idx, flag);
    k_transpose<<<dim3(IN_FT / 32, B_SZ / 32), dim3(32, 8), 0, stream>>>(x, xT, B_SZ, IN_FT);
    k_pack<<<(NNZ_TOT + 255) / 256, 256, 0, stream>>>(st_idx, st_vals, sn_idx, sn_vals,
                                                      flag, ent);
    k_gf<<<256, 1024, 131072, stream>>>(xT, ent, out);
}